// Round 9
// baseline (219.836 us; speedup 1.0000x reference)
//
#include <hip/hip_runtime.h>
#include <math.h>

// TopKRouter: x[16384,2048] fp32, W[64,2048] fp32
// out: [0..32767] top2 indices (as float), [32768..65535] gates, [65536] aux
// Split-fp16 MFMA (3-term: xh*wh + xh*wl + xl*wh).
// R9: two-pass split. R7 (TMB=64, 1 blk/CU, ~1024 VMEM instrs) = best at
// ~65us GEMM but 1 wave/SIMD (stalls exposed). R8 put 2 K-half waves in ONE
// block -> shared s_barrier domain -> no stall covering (+6us). R9 makes the
// K-halves INDEPENDENT blocks: gemm 512 blocks (2/CU, separate barrier
// domains, 2 waves/SIMD interleave), partial logits to ws (2x4MB); then a
// softmax kernel sums halves + identical verified top2/aux. Same per-CU
// VMEM instr count as R7; machinery (frag-linear XOR-swz LDS staging,
// reg x-ring depth2, reg W-ring dist2, lgkm-only barriers) unchanged.
#define NTOK 16384
#define DDIM 2048
#define NEXP 64
#define TMB  64                 // tokens per gemm block (4 MFMA M-tiles)
#define NCHH 16                 // K chunks of 64 per K-half
#define NSH  32                 // K32 steps per K-half

typedef _Float16 half8v __attribute__((ext_vector_type(8)));
typedef float    f32x4  __attribute__((ext_vector_type(4)));

#define MFMA16(a, b, c) __builtin_amdgcn_mfma_f32_16x16x32_f16((a), (b), (c), 0, 0, 0)

// W prep: fp32 -> (wh, wl) fp16 in MFMA-B fragment-linear layout (r5-verified):
// element (e,k): S=k>>5, nb=e>>4, nl=e&15, q=(k>>3)&3, j=k&7
// off = S*2048 + nb*512 + q*128 + nl*8 + j
__global__ __launch_bounds__(256) void prep_kernel(const float* __restrict__ W,
                                                   _Float16* __restrict__ Wh,
                                                   _Float16* __restrict__ Wl,
                                                   float* __restrict__ accg) {
    int idx = blockIdx.x * 256 + threadIdx.x;   // 64 blocks -> 16384 threads
    int e  = idx >> 8;                          // 0..63
    int k0 = (idx & 255) << 3;                  // 0..2040, multiple of 8
    const float* wp = W + (size_t)e * DDIM + k0;
    float4 w0 = *(const float4*)wp;
    float4 w1 = *(const float4*)(wp + 4);
    half8v h, l;
    h[0] = (_Float16)w0.x; l[0] = (_Float16)(w0.x - (float)h[0]);
    h[1] = (_Float16)w0.y; l[1] = (_Float16)(w0.y - (float)h[1]);
    h[2] = (_Float16)w0.z; l[2] = (_Float16)(w0.z - (float)h[2]);
    h[3] = (_Float16)w0.w; l[3] = (_Float16)(w0.w - (float)h[3]);
    h[4] = (_Float16)w1.x; l[4] = (_Float16)(w1.x - (float)h[4]);
    h[5] = (_Float16)w1.y; l[5] = (_Float16)(w1.y - (float)h[5]);
    h[6] = (_Float16)w1.z; l[6] = (_Float16)(w1.z - (float)h[6]);
    h[7] = (_Float16)w1.w; l[7] = (_Float16)(w1.w - (float)h[7]);
    int S = k0 >> 5, nb = e >> 4, nl = e & 15, q = (k0 >> 3) & 3;
    size_t off = (size_t)S * 2048 + nb * 512 + q * 128 + nl * 8;
    *(half8v*)&Wh[off] = h;
    *(half8v*)&Wl[off] = l;
    if (idx < 128) accg[idx] = 0.0f;
}

// convert 8 consecutive fp32 (one full 16B LDS granule) -> h,l half8v
__device__ __forceinline__ void cvt8(float4 a, float4 b, half8v& h, half8v& l) {
    h[0]=(_Float16)a.x; l[0]=(_Float16)(a.x-(float)h[0]);
    h[1]=(_Float16)a.y; l[1]=(_Float16)(a.y-(float)h[1]);
    h[2]=(_Float16)a.z; l[2]=(_Float16)(a.z-(float)h[2]);
    h[3]=(_Float16)a.w; l[3]=(_Float16)(a.w-(float)h[3]);
    h[4]=(_Float16)b.x; l[4]=(_Float16)(b.x-(float)h[4]);
    h[5]=(_Float16)b.y; l[5]=(_Float16)(b.y-(float)h[5]);
    h[6]=(_Float16)b.z; l[6]=(_Float16)(b.z-(float)h[6]);
    h[7]=(_Float16)b.w; l[7]=(_Float16)(b.w-(float)h[7]);
}

// GEMM pass: block b -> token tile tb=b>>1 (64 tokens), K-half kh=b&1.
// Writes partial logits P[kh][tok][exp] (fp32, dense 64-wide rows).
__global__ __launch_bounds__(256, 2) void gemm_kernel(
    const float* __restrict__ x, const _Float16* __restrict__ Wh,
    const _Float16* __restrict__ Wl, float* __restrict__ P)
{
    __shared__ __align__(16) _Float16 Ah[2][4096];   // 16 KB
    __shared__ __align__(16) _Float16 Al[2][4096];   // 16 KB

    const int tid  = threadIdx.x;
    const int lane = tid & 63;
    const int wv   = __builtin_amdgcn_readfirstlane(tid >> 6);  // expert block 0..3
    const int tb   = blockIdx.x >> 1;
    const int kh   = blockIdx.x & 1;
    const int m0   = tb * TMB;

    // ---- staging map: thread t -> row r=t>>2 (0..63), cols c0l..c0l+15 ----
    const int r    = tid >> 2;
    const int c0l  = (tid & 3) * 16;
    const int tile = r >> 4, tok = r & 15;
    const int S0 = c0l >> 5,       q0 = (c0l >> 3) & 3;
    const int S1 = (c0l+8) >> 5,   q1 = ((c0l+8) >> 3) & 3;
    const int g0 = S0*64 + q0*16 + tok,  g1 = S1*64 + q1*16 + tok;
    const int off0 = tile*1024 + (g0 ^ ((g0>>4)&7)) * 8;
    const int off1 = tile*1024 + (g1 ^ ((g1>>4)&7)) * 8;

    const float* gx = x + (size_t)(m0 + r) * DDIM + kh * 1024 + c0l;

    // ---- read-side swizzled offsets (per tile add tile*1024) ----
    const int gr1 = 64 + lane;
    const int rd0 = (lane ^ ((lane>>4)&7)) * 8;
    const int rd1 = (gr1 ^ ((gr1>>4)&7)) * 8;

    // W-frag pointers: K-half base kh*32 steps, expert block wv
    const _Float16* whp = Wh + (size_t)kh * 65536 + wv * 512 + lane * 8;
    const _Float16* wlp = Wl + (size_t)kh * 65536 + wv * 512 + lane * 8;

    f32x4 acc0 = {0.f,0.f,0.f,0.f}, acc1 = {0.f,0.f,0.f,0.f};
    f32x4 acc2 = {0.f,0.f,0.f,0.f}, acc3 = {0.f,0.f,0.f,0.f};

    // ---- prologue: x ring depth 2 (chunks 0,1), W ring 4 slots (steps 0..3)
    float4 xa0 = *(const float4*)(gx +  0), xa1 = *(const float4*)(gx +  4);
    float4 xa2 = *(const float4*)(gx +  8), xa3 = *(const float4*)(gx + 12);
    float4 xb0 = *(const float4*)(gx + 64), xb1 = *(const float4*)(gx + 68);
    float4 xb2 = *(const float4*)(gx + 72), xb3 = *(const float4*)(gx + 76);
    half8v wh0 = *(const half8v*)(whp);
    half8v wh1 = *(const half8v*)(whp + 2048);
    half8v wh2 = *(const half8v*)(whp + 4096);
    half8v wh3 = *(const half8v*)(whp + 6144);
    half8v wl0 = *(const half8v*)(wlp);
    half8v wl1 = *(const half8v*)(wlp + 2048);
    half8v wl2 = *(const half8v*)(wlp + 4096);
    half8v wl3 = *(const half8v*)(wlp + 6144);

#define CHUNK(ch, X0, X1, X2, X3, PB, WHA, WLA, WHB, WLB)                   \
    {                                                                        \
        half8v h_, l_;                                                       \
        cvt8(X0, X1, h_, l_);                                                \
        *(half8v*)&Ah[PB][off0] = h_;  *(half8v*)&Al[PB][off0] = l_;         \
        cvt8(X2, X3, h_, l_);                                                \
        *(half8v*)&Ah[PB][off1] = h_;  *(half8v*)&Al[PB][off1] = l_;         \
        const int cf = ((ch) + 2 < NCHH) ? (ch) + 2 : 0;                     \
        X0 = *(const float4*)(gx + cf * 64 +  0);                            \
        X1 = *(const float4*)(gx + cf * 64 +  4);                            \
        X2 = *(const float4*)(gx + cf * 64 +  8);                            \
        X3 = *(const float4*)(gx + cf * 64 + 12);                            \
        asm volatile("s_waitcnt lgkmcnt(0)" ::: "memory");                   \
        __builtin_amdgcn_s_barrier();                                        \
        {   /* step 2*ch */                                                  \
            half8v a0h = *(const half8v*)&Ah[PB][   0 + rd0];                \
            half8v a0l = *(const half8v*)&Al[PB][   0 + rd0];                \
            half8v a1h = *(const half8v*)&Ah[PB][1024 + rd0];                \
            half8v a1l = *(const half8v*)&Al[PB][1024 + rd0];                \
            half8v a2h = *(const half8v*)&Ah[PB][2048 + rd0];                \
            half8v a2l = *(const half8v*)&Al[PB][2048 + rd0];                \
            half8v a3h = *(const half8v*)&Ah[PB][3072 + rd0];                \
            half8v a3l = *(const half8v*)&Al[PB][3072 + rd0];                \
            half8v bh = WHA, bl = WLA;                                       \
            const int SgN = (2 * (ch) + 4) & (NSH - 1);                      \
            WHA = *(const half8v*)(whp + (size_t)SgN * 2048);                \
            WLA = *(const half8v*)(wlp + (size_t)SgN * 2048);                \
            acc0 = MFMA16(a0l, bh, acc0);                                    \
            acc0 = MFMA16(a0h, bl, acc0);                                    \
            acc0 = MFMA16(a0h, bh, acc0);                                    \
            acc1 = MFMA16(a1l, bh, acc1);                                    \
            acc1 = MFMA16(a1h, bl, acc1);                                    \
            acc1 = MFMA16(a1h, bh, acc1);                                    \
            acc2 = MFMA16(a2l, bh, acc2);                                    \
            acc2 = MFMA16(a2h, bl, acc2);                                    \
            acc2 = MFMA16(a2h, bh, acc2);                                    \
            acc3 = MFMA16(a3l, bh, acc3);                                    \
            acc3 = MFMA16(a3h, bl, acc3);                                    \
            acc3 = MFMA16(a3h, bh, acc3);                                    \
        }                                                                    \
        {   /* step 2*ch+1 */                                                \
            half8v a0h = *(const half8v*)&Ah[PB][   0 + rd1];                \
            half8v a0l = *(const half8v*)&Al[PB][   0 + rd1];                \
            half8v a1h = *(const half8v*)&Ah[PB][1024 + rd1];                \
            half8v a1l = *(const half8v*)&Al[PB][1024 + rd1];                \
            half8v a2h = *(const half8v*)&Ah[PB][2048 + rd1];                \
            half8v a2l = *(const half8v*)&Al[PB][2048 + rd1];                \
            half8v a3h = *(const half8v*)&Ah[PB][3072 + rd1];                \
            half8v a3l = *(const half8v*)&Al[PB][3072 + rd1];                \
            half8v bh = WHB, bl = WLB;                                       \
            const int SgN = (2 * (ch) + 5) & (NSH - 1);                      \
            WHB = *(const half8v*)(whp + (size_t)SgN * 2048);                \
            WLB = *(const half8v*)(wlp + (size_t)SgN * 2048);                \
            acc0 = MFMA16(a0l, bh, acc0);                                    \
            acc0 = MFMA16(a0h, bl, acc0);                                    \
            acc0 = MFMA16(a0h, bh, acc0);                                    \
            acc1 = MFMA16(a1l, bh, acc1);                                    \
            acc1 = MFMA16(a1h, bl, acc1);                                    \
            acc1 = MFMA16(a1h, bh, acc1);                                    \
            acc2 = MFMA16(a2l, bh, acc2);                                    \
            acc2 = MFMA16(a2h, bl, acc2);                                    \
            acc2 = MFMA16(a2h, bh, acc2);                                    \
            acc3 = MFMA16(a3l, bh, acc3);                                    \
            acc3 = MFMA16(a3h, bl, acc3);                                    \
            acc3 = MFMA16(a3h, bh, acc3);                                    \
        }                                                                    \
        asm volatile("s_waitcnt lgkmcnt(0)" ::: "memory");                   \
        __builtin_amdgcn_s_barrier();                                        \
    }

    for (int cb = 0; cb < NCHH; cb += 2) {
        CHUNK(cb + 0, xa0, xa1, xa2, xa3, 0, wh0, wl0, wh1, wl1);
        CHUNK(cb + 1, xb0, xb1, xb2, xb3, 1, wh2, wl2, wh3, wl3);
    }
#undef CHUNK

    // ---- direct partial-logit store. C layout: row m=(lane>>4)*4+rr,
    // col n=lane&15 (m89/r5-verified). 16-lane groups write 64B segments.
    {
        const int qr = lane >> 4;
        const int nl = lane & 15;
        float* gp = P + (size_t)kh * NTOK * NEXP
                      + (size_t)(m0 + qr * 4) * NEXP + wv * 16 + nl;
        #pragma unroll
        for (int rr = 0; rr < 4; ++rr) {
            gp[(      rr) * NEXP] = acc0[rr];
            gp[(16  + rr) * NEXP] = acc1[rr];
            gp[(32  + rr) * NEXP] = acc2[rr];
            gp[(48  + rr) * NEXP] = acc3[rr];
        }
    }
}

// Softmax pass: 32 tokens/block; sums the two K-half partials, then the
// verified softmax + top-2 + aux accumulation.
__global__ __launch_bounds__(256) void softmax_kernel(
    const float* __restrict__ P, float* __restrict__ accg,
    float* __restrict__ out)
{
    __shared__ float prb[32][NEXP + 1];   // 8.3 KB
    __shared__ float cnt[NEXP];

    const int tid = threadIdx.x;
    const int m0  = blockIdx.x * 32;
    if (tid < NEXP) cnt[tid] = 0.0f;
    __syncthreads();

    const int m = tid >> 3;
    const int j = tid & 7;
    const float* pa = P + (size_t)(m0 + m) * NEXP + j * 8;
    const float* pb = pa + (size_t)NTOK * NEXP;
    float4 a0 = *(const float4*)pa,       a1 = *(const float4*)(pa + 4);
    float4 b0 = *(const float4*)pb,       b1 = *(const float4*)(pb + 4);
    float l[8] = { a0.x + b0.x, a0.y + b0.y, a0.z + b0.z, a0.w + b0.w,
                   a1.x + b1.x, a1.y + b1.y, a1.z + b1.z, a1.w + b1.w };

    float mx = l[0];
    #pragma unroll
    for (int i = 1; i < 8; ++i) mx = fmaxf(mx, l[i]);
    #pragma unroll
    for (int off = 1; off < 8; off <<= 1) mx = fmaxf(mx, __shfl_xor(mx, off, 8));

    float ev[8];
    float zs = 0.f;
    float v1 = -INFINITY, v2 = -INFINITY;
    int i1 = 0, i2 = 0;
    #pragma unroll
    for (int i = 0; i < 8; ++i) {
        ev[i] = __expf(l[i] - mx);
        zs += ev[i];
        int e = j * 8 + i;
        if (l[i] > v1)      { v2 = v1; i2 = i1; v1 = l[i]; i1 = e; }
        else if (l[i] > v2) { v2 = l[i]; i2 = e; }
    }
    #pragma unroll
    for (int off = 1; off < 8; off <<= 1) zs += __shfl_xor(zs, off, 8);

    // merge top-2 across 8 lanes (value desc, index asc on ties = lax.top_k)
    #pragma unroll
    for (int off = 1; off < 8; off <<= 1) {
        float ov1 = __shfl_xor(v1, off, 8);
        int   oi1 = __shfl_xor(i1, off, 8);
        float ov2 = __shfl_xor(v2, off, 8);
        int   oi2 = __shfl_xor(i2, off, 8);
        bool afirst = (v1 > ov1) || (v1 == ov1 && i1 < oi1);
        if (afirst) {
            bool t = (v2 > ov1) || (v2 == ov1 && i2 < oi1);
            v2 = t ? v2 : ov1;
            i2 = t ? i2 : oi1;
        } else {
            bool t = (ov2 > v1) || (ov2 == v1 && oi2 < i1);
            v2 = t ? ov2 : v1;
            i2 = t ? oi2 : i1;
            v1 = ov1;
            i1 = oi1;
        }
    }

    const float invz = 1.0f / zs;
    if (j == 0) {
        float p1 = invz;                      // v1 == mx exactly
        float p2 = __expf(v2 - mx) * invz;
        float sden = p1 + p2 + 1e-9f;
        int tokg = m0 + m;
        out[tokg * 2 + 0] = (float)i1;
        out[tokg * 2 + 1] = (float)i2;
        out[32768 + tokg * 2 + 0] = p1 / sden;
        out[32768 + tokg * 2 + 1] = p2 / sden;
        atomicAdd(&cnt[i1], 1.0f);
        atomicAdd(&cnt[i2], 1.0f);
    }

    // probs writeback (own slots only)
    #pragma unroll
    for (int i = 0; i < 8; ++i) prb[m][j * 8 + i] = ev[i] * invz;
    __syncthreads();

    // global accumulators (accg zeroed by prep each launch)
    if (tid < NEXP) {
        atomicAdd(&accg[tid], cnt[tid]);
    } else if (tid < 128) {
        int e = tid - 64;
        float s = 0.f;
        #pragma unroll
        for (int t = 0; t < 32; ++t) s += prb[t][e];
        atomicAdd(&accg[64 + e], s);
    }
}

__global__ void finalize_kernel(const float* __restrict__ accg,
                                float* __restrict__ out)
{
    int t = threadIdx.x;   // 64 threads
    float c = accg[t];
    float p = accg[64 + t];
    float term = (c / (float)(NTOK * 2)) * (p / (float)NTOK);
    #pragma unroll
    for (int off = 1; off < 64; off <<= 1) term += __shfl_xor(term, off, 64);
    if (t == 0) out[65536] = 0.01f * (float)NEXP * term;
}

extern "C" void kernel_launch(void* const* d_in, const int* in_sizes, int n_in,
                              void* d_out, int out_size, void* d_ws, size_t ws_size,
                              hipStream_t stream) {
    const float* x = (const float*)d_in[0];   // [4,4096,2048]
    const float* W = (const float*)d_in[1];   // [64,2048]
    float* out  = (float*)d_out;              // 65537 floats
    float* accg = (float*)d_ws;               // 128 floats
    _Float16* Wh = (_Float16*)(accg + 128);   // 131072 halfs (256 KB)
    _Float16* Wl = Wh + (size_t)DDIM * NEXP;  // 131072 halfs (256 KB)
    float* P    = (float*)(Wl + (size_t)DDIM * NEXP);  // 2 x 4 MB partials

    prep_kernel<<<64, 256, 0, stream>>>(W, Wh, Wl, accg);
    gemm_kernel<<<512, 256, 0, stream>>>(x, Wh, Wl, P);
    softmax_kernel<<<512, 256, 0, stream>>>(P, accg, out);
    finalize_kernel<<<1, 64, 0, stream>>>(accg, out);
}

// Round 10
// 207.956 us; speedup vs baseline: 1.0571x; 1.0571x over previous
//
#include <hip/hip_runtime.h>
#include <math.h>

// TopKRouter: x[16384,2048] fp32, W[64,2048] fp32
// out: [0..32767] top2 indices (as float), [32768..65535] gates, [65536] aux
// Split-fp16 MFMA (3-term: xh*wh + xh*wl + xl*wh).
// R10: SINGLE-KERNEL fusion. Cost model from R3..R9: total = router + 141.7us
// fixed (one 512MB ws-poison fill ~78 + prep ~8 + ~4 launch gaps @ ~10-12us,
// measured by R9's +1-launch regression). GEMM is invariant at ~65us across
// 10 structures -> attack the fixed cost instead:
//  - prep_kernel deleted: W loaded directly as fp32 in the W-ring and
//    converted (h,l) in-register (same VMEM instr count & bytes; +24 VALU/step)
//  - finalize_kernel deleted: device-scope ticket; last block computes aux
//  - accg+ticket zeroed via tiny hipMemsetAsync (graph-capturable)
// GEMM machinery byte-for-byte R7 (best measured: 207.2us total): TMB=64,
// 256 blocks (1/CU), frag-linear XOR-swz LDS staging, x-ring depth 2,
// W-ring distance 2, lgkm-only barriers, verified C-layout/softmax/top-2.
#define NTOK 16384
#define DDIM 2048
#define NEXP 64
#define TMB  64                 // tokens per block (4 MFMA M-tiles)
#define NBLK (NTOK / TMB)       // 256 blocks -> 1 block/CU
#define NCH  32                 // K chunks of 64
#define NS   64                 // K32 MFMA steps total

typedef _Float16 half8v __attribute__((ext_vector_type(8)));
typedef float    f32x4  __attribute__((ext_vector_type(4)));

#define MFMA16(a, b, c) __builtin_amdgcn_mfma_f32_16x16x32_f16((a), (b), (c), 0, 0, 0)

// convert 8 consecutive fp32 -> (high fp16, residual fp16)
__device__ __forceinline__ void cvt8(float4 a, float4 b, half8v& h, half8v& l) {
    h[0]=(_Float16)a.x; l[0]=(_Float16)(a.x-(float)h[0]);
    h[1]=(_Float16)a.y; l[1]=(_Float16)(a.y-(float)h[1]);
    h[2]=(_Float16)a.z; l[2]=(_Float16)(a.z-(float)h[2]);
    h[3]=(_Float16)a.w; l[3]=(_Float16)(a.w-(float)h[3]);
    h[4]=(_Float16)b.x; l[4]=(_Float16)(b.x-(float)h[4]);
    h[5]=(_Float16)b.y; l[5]=(_Float16)(b.y-(float)h[5]);
    h[6]=(_Float16)b.z; l[6]=(_Float16)(b.z-(float)h[6]);
    h[7]=(_Float16)b.w; l[7]=(_Float16)(b.w-(float)h[7]);
}

__global__ __launch_bounds__(256, 1) void router_kernel(
    const float* __restrict__ x, const float* __restrict__ W,
    float* __restrict__ accg, float* __restrict__ out)
{
    __shared__ __align__(16) _Float16 Ah[2][4096];   // 16 KB
    __shared__ __align__(16) _Float16 Al[2][4096];   // 16 KB
    __shared__ float lgt[TMB][NEXP + 1];             // 16.6 KB
    __shared__ float cnt[NEXP];
    __shared__ int lastBlk;

    const int tid  = threadIdx.x;
    const int lane = tid & 63;
    const int wv   = __builtin_amdgcn_readfirstlane(tid >> 6);  // expert block 0..3
    const int m0   = blockIdx.x * TMB;

    if (tid < NEXP) cnt[tid] = 0.0f;

    // ---- staging map: thread t -> row r=t>>2 (0..63), cols c0..c0+15 ----
    const int r    = tid >> 2;
    const int c0   = (tid & 3) * 16;
    const int tile = r >> 4, tok = r & 15;
    const int S0 = c0 >> 5,       q0 = (c0 >> 3) & 3;
    const int S1 = (c0+8) >> 5,   q1 = ((c0+8) >> 3) & 3;
    const int g0 = S0*64 + q0*16 + tok,  g1 = S1*64 + q1*16 + tok;
    const int off0 = tile*1024 + (g0 ^ ((g0>>4)&7)) * 8;
    const int off1 = tile*1024 + (g1 ^ ((g1>>4)&7)) * 8;

    const float* gx = x + (size_t)(m0 + r) * DDIM + c0;

    // ---- read-side swizzled offsets (per tile add tile*1024) ----
    const int gr1 = 64 + lane;
    const int rd0 = (lane ^ ((lane>>4)&7)) * 8;
    const int rd1 = (gr1 ^ ((gr1>>4)&7)) * 8;

    // ---- W direct fp32: B-frag lane (q=lane>>4, nl=lane&15) holds
    // expert e = wv*16+nl, k = Sg*32 + q*8 + j  (prep-layout equivalent) ----
    const float* wfp = W + (size_t)(wv * 16 + (lane & 15)) * DDIM + (lane >> 4) * 8;

    f32x4 acc0 = {0.f,0.f,0.f,0.f}, acc1 = {0.f,0.f,0.f,0.f};
    f32x4 acc2 = {0.f,0.f,0.f,0.f}, acc3 = {0.f,0.f,0.f,0.f};

    // ---- prologue: x ring depth 2 (chunks 0,1); W ring 4 slots (steps 0..3)
    float4 xa0 = *(const float4*)(gx +  0), xa1 = *(const float4*)(gx +  4);
    float4 xa2 = *(const float4*)(gx +  8), xa3 = *(const float4*)(gx + 12);
    float4 xb0 = *(const float4*)(gx + 64), xb1 = *(const float4*)(gx + 68);
    float4 xb2 = *(const float4*)(gx + 72), xb3 = *(const float4*)(gx + 76);
    float4 w0a = *(const float4*)(wfp +  0), w0b = *(const float4*)(wfp +  4);
    float4 w1a = *(const float4*)(wfp + 32), w1b = *(const float4*)(wfp + 36);
    float4 w2a = *(const float4*)(wfp + 64), w2b = *(const float4*)(wfp + 68);
    float4 w3a = *(const float4*)(wfp + 96), w3b = *(const float4*)(wfp + 100);

#define STEPBODY(RD, BH, BL)                                                 \
    {                                                                        \
        half8v a0h = *(const half8v*)&Ah[PB_][   0 + RD];                    \
        half8v a0l = *(const half8v*)&Al[PB_][   0 + RD];                    \
        half8v a1h = *(const half8v*)&Ah[PB_][1024 + RD];                    \
        half8v a1l = *(const half8v*)&Al[PB_][1024 + RD];                    \
        half8v a2h = *(const half8v*)&Ah[PB_][2048 + RD];                    \
        half8v a2l = *(const half8v*)&Al[PB_][2048 + RD];                    \
        half8v a3h = *(const half8v*)&Ah[PB_][3072 + RD];                    \
        half8v a3l = *(const half8v*)&Al[PB_][3072 + RD];                    \
        acc0 = MFMA16(a0l, BH, acc0);                                        \
        acc0 = MFMA16(a0h, BL, acc0);                                        \
        acc0 = MFMA16(a0h, BH, acc0);                                        \
        acc1 = MFMA16(a1l, BH, acc1);                                        \
        acc1 = MFMA16(a1h, BL, acc1);                                        \
        acc1 = MFMA16(a1h, BH, acc1);                                        \
        acc2 = MFMA16(a2l, BH, acc2);                                        \
        acc2 = MFMA16(a2h, BL, acc2);                                        \
        acc2 = MFMA16(a2h, BH, acc2);                                        \
        acc3 = MFMA16(a3l, BH, acc3);                                        \
        acc3 = MFMA16(a3h, BL, acc3);                                        \
        acc3 = MFMA16(a3h, BH, acc3);                                        \
    }

#define CHUNK(ch, X0, X1, X2, X3, PB, WAa, WAb, WBa, WBb)                   \
    {                                                                        \
        const int PB_ = (PB);                                                \
        half8v h_, l_;                                                       \
        cvt8(X0, X1, h_, l_);                                                \
        *(half8v*)&Ah[PB_][off0] = h_;  *(half8v*)&Al[PB_][off0] = l_;       \
        cvt8(X2, X3, h_, l_);                                                \
        *(half8v*)&Ah[PB_][off1] = h_;  *(half8v*)&Al[PB_][off1] = l_;       \
        const int cf = ((ch) + 2 < NCH) ? (ch) + 2 : 0;                      \
        X0 = *(const float4*)(gx + cf * 64 +  0);                            \
        X1 = *(const float4*)(gx + cf * 64 +  4);                            \
        X2 = *(const float4*)(gx + cf * 64 +  8);                            \
        X3 = *(const float4*)(gx + cf * 64 + 12);                            \
        asm volatile("s_waitcnt lgkmcnt(0)" ::: "memory");                   \
        __builtin_amdgcn_s_barrier();                                        \
        {   /* step Sg = 2*ch */                                             \
            half8v bh, bl;                                                   \
            cvt8(WAa, WAb, bh, bl);                                          \
            const int SgN = (2 * (ch) + 4) & (NS - 1);                       \
            WAa = *(const float4*)(wfp + SgN * 32);                          \
            WAb = *(const float4*)(wfp + SgN * 32 + 4);                      \
            STEPBODY(rd0, bh, bl)                                            \
        }                                                                    \
        {   /* step Sg = 2*ch+1 */                                           \
            half8v bh, bl;                                                   \
            cvt8(WBa, WBb, bh, bl);                                          \
            const int SgN = (2 * (ch) + 5) & (NS - 1);                       \
            WBa = *(const float4*)(wfp + SgN * 32);                          \
            WBb = *(const float4*)(wfp + SgN * 32 + 4);                      \
            STEPBODY(rd1, bh, bl)                                            \
        }                                                                    \
        asm volatile("s_waitcnt lgkmcnt(0)" ::: "memory");                   \
        __builtin_amdgcn_s_barrier();                                        \
    }

    for (int cb = 0; cb < NCH; cb += 2) {
        CHUNK(cb + 0, xa0, xa1, xa2, xa3, 0, w0a, w0b, w1a, w1b);
        CHUNK(cb + 1, xb0, xb1, xb2, xb3, 1, w2a, w2b, w3a, w3b);
    }
#undef CHUNK
#undef STEPBODY

    // ---- C layout: row m=(lane>>4)*4+rr, col n=lane&15 (m89/r5-verified) ----
    {
        const int qr = lane >> 4;
        const int nl = lane & 15;
        #pragma unroll
        for (int rr = 0; rr < 4; ++rr) {
            const int mm = qr * 4 + rr;
            lgt[ 0 + mm][wv * 16 + nl] = acc0[rr];
            lgt[16 + mm][wv * 16 + nl] = acc1[rr];
            lgt[32 + mm][wv * 16 + nl] = acc2[rr];
            lgt[48 + mm][wv * 16 + nl] = acc3[rr];
        }
    }
    __syncthreads();

    // ---- softmax + top-2: 8 threads/token, 2 passes of 32 tokens ----
    for (int pass = 0; pass < 2; ++pass) {
        const int m = pass * 32 + (tid >> 3);
        const int j = tid & 7;
        float l[8];
        #pragma unroll
        for (int i = 0; i < 8; ++i) l[i] = lgt[m][j * 8 + i];

        float mx = l[0];
        #pragma unroll
        for (int i = 1; i < 8; ++i) mx = fmaxf(mx, l[i]);
        #pragma unroll
        for (int off = 1; off < 8; off <<= 1) mx = fmaxf(mx, __shfl_xor(mx, off, 8));

        float ev[8];
        float zs = 0.f;
        float v1 = -INFINITY, v2 = -INFINITY;
        int i1 = 0, i2 = 0;
        #pragma unroll
        for (int i = 0; i < 8; ++i) {
            ev[i] = __expf(l[i] - mx);
            zs += ev[i];
            int e = j * 8 + i;
            if (l[i] > v1)      { v2 = v1; i2 = i1; v1 = l[i]; i1 = e; }
            else if (l[i] > v2) { v2 = l[i]; i2 = e; }
        }
        #pragma unroll
        for (int off = 1; off < 8; off <<= 1) zs += __shfl_xor(zs, off, 8);

        // merge top-2 across 8 lanes (value desc, index asc on ties = lax.top_k)
        #pragma unroll
        for (int off = 1; off < 8; off <<= 1) {
            float ov1 = __shfl_xor(v1, off, 8);
            int   oi1 = __shfl_xor(i1, off, 8);
            float ov2 = __shfl_xor(v2, off, 8);
            int   oi2 = __shfl_xor(i2, off, 8);
            bool afirst = (v1 > ov1) || (v1 == ov1 && i1 < oi1);
            if (afirst) {
                bool t = (v2 > ov1) || (v2 == ov1 && i2 < oi1);
                v2 = t ? v2 : ov1;
                i2 = t ? i2 : oi1;
            } else {
                bool t = (ov2 > v1) || (ov2 == v1 && oi2 < i1);
                v2 = t ? ov2 : v1;
                i2 = t ? oi2 : i1;
                v1 = ov1;
                i1 = oi1;
            }
        }

        const float invz = 1.0f / zs;
        if (j == 0) {
            float p1 = invz;                      // v1 == mx exactly
            float p2 = __expf(v2 - mx) * invz;
            float sden = p1 + p2 + 1e-9f;
            int tokg = m0 + m;
            out[tokg * 2 + 0] = (float)i1;
            out[tokg * 2 + 1] = (float)i2;
            out[32768 + tokg * 2 + 0] = p1 / sden;
            out[32768 + tokg * 2 + 1] = p2 / sden;
            atomicAdd(&cnt[i1], 1.0f);
            atomicAdd(&cnt[i2], 1.0f);
        }

        // probs writeback (own slots only)
        #pragma unroll
        for (int i = 0; i < 8; ++i) lgt[m][j * 8 + i] = ev[i] * invz;
    }
    __syncthreads();

    // global accumulators (accg zeroed by host-side memset each launch)
    if (tid < NEXP) {
        atomicAdd(&accg[tid], cnt[tid]);
    } else if (tid < 128) {
        int e = tid - 64;
        float s = 0.f;
        #pragma unroll
        for (int t = 0; t < TMB; ++t) s += lgt[t][e];
        atomicAdd(&accg[64 + e], s);
    }
    __syncthreads();

    // ---- last-block aux finalize (device-scope ticket) ----
    if (tid == 0) {
        __threadfence();   // release: our accg atomics visible before ticket
        unsigned int old = atomicAdd((unsigned int*)(accg + 128), 1u);
        lastBlk = (old == NBLK - 1) ? 1 : 0;
    }
    __syncthreads();
    if (lastBlk && tid < 64) {
        __threadfence();   // acquire: invalidate L1 before reading accg
        const volatile float* ag = accg;
        float c = ag[tid];
        float p = ag[64 + tid];
        float term = (c / (float)(NTOK * 2)) * (p / (float)NTOK);
        #pragma unroll
        for (int off = 1; off < 64; off <<= 1) term += __shfl_xor(term, off, 64);
        if (tid == 0) out[65536] = 0.01f * (float)NEXP * term;
    }
}

extern "C" void kernel_launch(void* const* d_in, const int* in_sizes, int n_in,
                              void* d_out, int out_size, void* d_ws, size_t ws_size,
                              hipStream_t stream) {
    const float* x = (const float*)d_in[0];   // [4,4096,2048]
    const float* W = (const float*)d_in[1];   // [64,2048]
    float* out  = (float*)d_out;              // 65537 floats
    float* accg = (float*)d_ws;               // 128 floats + ticket

    hipMemsetAsync(accg, 0, 1024, stream);    // counts, probsums, ticket
    router_kernel<<<NBLK, 256, 0, stream>>>(x, W, accg, out);
}